// Round 11
// baseline (5294.136 us; speedup 1.0000x reference)
//
#include <hip/hip_runtime.h>
#include <cstdint>
#include <cstddef>
#include <string.h>

typedef __bf16 bf16;
typedef bf16 bf16x4 __attribute__((ext_vector_type(4)));
typedef bf16 bf16x8 __attribute__((ext_vector_type(8)));
typedef float f32x4 __attribute__((ext_vector_type(4)));
typedef unsigned long long u64;

#define B_   64
#define T_   512
#define I_   1024
#define H_   1024
#define BT_  32768
#define NBL  64    // lstm blocks
#define NJ   16    // hidden units per lstm block

// ---- ws layout (bytes) ----
#define WS_XBF   ((size_t)0)              // x as bf16 [32768][1024]            : 67108864
#define WS_WXP   ((size_t)67108864)       // Wx^T bf16 [4096][1024]             : 8388608
#define WS_WHP   ((size_t)75497472)       // Wh packed bf16 [64][128][64][8]    : 8388608
#define WS_XG    ((size_t)83886080)       // xg bf16 [512][64][64][64]          : 268435456
#define WS_HB    ((size_t)352321536)      // h dbuf bf16 [2][64][1024]          : 262144
#define WS_ARR   ((size_t)352583680)      // flags u32[8 wave][64 blk] @32B     : 16384
#define WS_NEED  ((size_t)352600064)

#define GLD_LDS16(gptr, lptr) \
  __builtin_amdgcn_global_load_lds((const __attribute__((address_space(1))) void*)(gptr), \
                                   (__attribute__((address_space(3))) void*)(lptr), 16, 0, 0)

__device__ __forceinline__ float sigmoidf_(float x) { return 1.0f / (1.0f + __expf(-x)); }
// branch-free tanh: 1 - 2/(e^{2x}+1); saturates correctly for |x| large (no NaN).
__device__ __forceinline__ float tanhf_(float x) { float e = __expf(2.0f * x); return 1.0f - 2.0f / (e + 1.0f); }
__device__ __forceinline__ float lo2f(unsigned u) { unsigned v = u << 16; float f; memcpy(&f, &v, 4); return f; }
__device__ __forceinline__ float hi2f(unsigned u) { unsigned v = u & 0xffff0000u; float f; memcpy(&f, &v, 4); return f; }
__device__ __forceinline__ unsigned short b2s(bf16 h) { unsigned short s; memcpy(&s, &h, 2); return s; }

// ---------------- pack kernels ----------------

__global__ __launch_bounds__(256) void k_cvt_x(const float4* __restrict__ in,
                                               bf16* __restrict__ out, int n4) {
  int i = blockIdx.x * blockDim.x + threadIdx.x;
  int stride = gridDim.x * blockDim.x;
  for (; i < n4; i += stride) {
    float4 v = in[i];
    bf16x4 r = { (bf16)v.x, (bf16)v.y, (bf16)v.z, (bf16)v.w };
    *(bf16x4*)(out + (size_t)i * 4) = r;
  }
}

// Wx^T: wxp[(gate*1024 + n)][k] = W[k][n]   (32x32 LDS tile transpose)
__global__ __launch_bounds__(256) void k_pack_wx(const float* __restrict__ W,
                                                 bf16* __restrict__ wxp, int gate) {
  __shared__ bf16 tile[32][33];
  int bx = blockIdx.x & 31, by = blockIdx.x >> 5;
  int tx = threadIdx.x & 31, ty = threadIdx.x >> 5;
  int k0 = by * 32, n0 = bx * 32;
  for (int r = 0; r < 32; r += 8)
    tile[ty + r][tx] = (bf16)W[(size_t)(k0 + ty + r) * H_ + n0 + tx];
  __syncthreads();
  for (int r = 0; r < 32; r += 8)
    wxp[(size_t)(gate * H_ + n0 + ty + r) * I_ + k0 + tx] = tile[tx][ty + r];
}

// Wh packed GATE-MAJOR: whp[blk][k>>3][gate*16 + (u&15)][k&7] = W[k][u]
__global__ __launch_bounds__(256) void k_pack_wh(const float* __restrict__ W,
                                                 bf16* __restrict__ whp, int gate) {
  __shared__ bf16 tile[32][33];
  int bx = blockIdx.x & 31, by = blockIdx.x >> 5;
  int tx = threadIdx.x & 31, ty = threadIdx.x >> 5;
  int k0 = by * 32, u0 = bx * 32;
  for (int r = 0; r < 32; r += 8)
    tile[ty + r][tx] = (bf16)W[(size_t)(k0 + ty + r) * H_ + u0 + tx];
  __syncthreads();
  for (int r = 0; r < 32; r += 8) {
    int u = u0 + ty + r;
    int k = k0 + tx;
    size_t addr = ((size_t)(u >> 4) * 128 + (k >> 3)) * 512 +
                  (size_t)(gate * 16 + (u & 15)) * 8 + (k & 7);
    whp[addr] = tile[tx][ty + r];
  }
}

// ---------------- phase 1: xg = x @ Wx  (bf16 MFMA, m97-style) ----------------
// xg written UNIT-MAJOR: xg[t][blk][row][ (u&15)*4 + gate ]
__global__ __launch_bounds__(256) void k_gemm_xg(const bf16* __restrict__ A,
                                                 const bf16* __restrict__ Bt,
                                                 bf16* __restrict__ xg) {
  __shared__ bf16 As[128 * 64];
  __shared__ bf16 Bs[128 * 64];
  int bid = blockIdx.x;
  int bm = bid >> 5, bn = bid & 31;
  int m0 = bm * 128, n0 = bn * 128;
  int tid = threadIdx.x, lane = tid & 63, w = tid >> 6;
  int lr = lane & 15, lk = lane >> 4;
  int sr = lane >> 3, sk = (lane & 7) * 8;
  int wm = (w >> 1) * 64, wn = (w & 1) * 64;
  f32x4 acc[4][4] = {};

  for (int k0 = 0; k0 < 1024; k0 += 64) {
    __syncthreads();
    for (int i = 0; i < 4; ++i) {
      int idx = w * 4 + i;
      const bf16* ga = A + (size_t)(m0 + idx * 8 + sr) * 1024 + k0 + sk;
      GLD_LDS16(ga, &As[idx * 512]);
      const bf16* gb = Bt + (size_t)(n0 + idx * 8 + sr) * 1024 + k0 + sk;
      GLD_LDS16(gb, &Bs[idx * 512]);
    }
    asm volatile("s_waitcnt vmcnt(0)" ::: "memory");
    __syncthreads();
#pragma unroll
    for (int kk = 0; kk < 64; kk += 32) {
      bf16x8 af[4], bfr[4];
#pragma unroll
      for (int i = 0; i < 4; ++i)
        af[i] = *(const bf16x8*)&As[(wm + i * 16 + lr) * 64 + kk + lk * 8];
#pragma unroll
      for (int j = 0; j < 4; ++j)
        bfr[j] = *(const bf16x8*)&Bs[(wn + j * 16 + lr) * 64 + kk + lk * 8];
#pragma unroll
      for (int i = 0; i < 4; ++i)
#pragma unroll
        for (int j = 0; j < 4; ++j)
          acc[i][j] = __builtin_amdgcn_mfma_f32_16x16x32_bf16(af[i], bfr[j], acc[i][j], 0, 0, 0);
    }
  }
  // epilogue: scatter into xg[t][blk][b][c],  blk = u>>4, c = (u&15)*4 + g
#pragma unroll
  for (int i = 0; i < 4; ++i) {
#pragma unroll
    for (int j = 0; j < 4; ++j) {
      int n = n0 + wn + j * 16 + lr;
      int u = n & 1023, g = n >> 10;
      int blk = u >> 4, c = (u & 15) * 4 + g;
      int mb = m0 + wm + i * 16 + lk * 4;
#pragma unroll
      for (int r = 0; r < 4; ++r) {
        int m = mb + r;
        int t = m & 511, bb = m >> 9;
        xg[(((size_t)t * NBL + blk) * B_ + bb) * 64 + c] = (bf16)acc[i][j][r];
      }
    }
  }
}

// ---------------- phase 2: zero-syncthreads dataflow at 8-wave occupancy ----------------
// 64 blocks x 512 threads (8 waves, 2/SIMD). Wave w owns batch rows w*8..w*8+7, FULL K,
// all 64 gate-cols. 16-row MFMA frames: rows 8-15 duplicate rows 0-7 (lr&7) — wave
// coalescer merges twin addresses, garbage C-rows discarded. Gate-major whl => lane
// (lk<2) holds complete acc[gate][r] for (row w*8+lk*4+r, unit lr): no gl, no
// syncthreads in steady state. 8 independent 64-block chains (one per wave index);
// per-wave flag after per-wave drain; 32B-sector publishes; xg prefetched pre-poll.
__global__ __launch_bounds__(512) void k_lstm(const bf16* __restrict__ xg,
                                              const bf16* __restrict__ whp,
                                              bf16* hb,              // [2][64][1024]
                                              float* __restrict__ out,
                                              unsigned* arr,         // [8 wave][64 blk] @32B
                                              const float* __restrict__ bii, const float* __restrict__ bhi,
                                              const float* __restrict__ bif, const float* __restrict__ bhf,
                                              const float* __restrict__ big, const float* __restrict__ bhg,
                                              const float* __restrict__ bio, const float* __restrict__ bho) {
  __shared__ bf16 whl[65536];          // 128 KB: [k>>3][c][k&7], c = g*16+u
  int blk = blockIdx.x;
  int tid = threadIdx.x;
  int lane = tid & 63, w = tid >> 6;
  int lr = lane & 15, lk = lane >> 4;

  {  // stage Wh slice: 128KB contiguous
    const bf16* src = whp + (size_t)blk * 65536;
#pragma unroll
    for (int i = 0; i < 16; ++i)
      *(bf16x8*)&whl[(size_t)(i * 512 + tid) * 8] = *(const bf16x8*)&src[(size_t)(i * 512 + tid) * 8];
  }

  int ug = blk * NJ + lr;              // unit owned by this lane
  f32x4 bias = { bii[ug] + bhi[ug], bif[ug] + bhf[ug],
                 big[ug] + bhg[ug], bio[ug] + bho[ug] };
  float cs[4] = {0.f, 0.f, 0.f, 0.f};

  const char* hb_c = (const char*)hb;
  const char* flg = (const char*)arr;
  const char* xg_c = (const char*)xg;
  int xrow = (w * 8 + lk * 4) & 63;    // valid rows for lk<2; wrapped (unused) for lk>=2
  __syncthreads();  // whl ready (only barrier in the kernel)

  // prefetch xg for t=0 (4 gates x bf16 = 8B per row, unit-major layout)
  u64 xq[4];
  {
    const char* xb = xg_c + (((size_t)0 * NBL + blk) * B_ + xrow) * 128 + (size_t)lr * 8;
#pragma unroll
    for (int r = 0; r < 4; ++r)
      asm volatile("global_load_dwordx2 %0, %1, off" : "=v"(xq[r]) : "v"(xb + (size_t)r * 128));
  }

  for (int t = 0; t < T_; ++t) {
    // ---- poll: same-wave-index flags of all 64 blocks >= t (xq drains under poll) ----
    if (t > 0) {
      const char* fp = flg + ((size_t)w * 64 + lane) * 32;
      unsigned fv; int cap = 0;
      do {
        asm volatile("global_load_dword %0, %1, off sc0 sc1\n\ts_waitcnt vmcnt(0)"
                     : "=v"(fv) : "v"(fp) : "memory");
      } while (!__all((int)(fv >= (unsigned)t)) && ++cap < 300000);
      __builtin_amdgcn_sched_barrier(0);
    }

    // ---- issue 32 A-loads: my 8 rows (lr&7 duplication), full K ----
    bf16x8 af[32];
    const char* hbase = hb_c + (size_t)(t & 1) * 131072 +
                        (size_t)(w * 8 + (lr & 7)) * 2048 + (size_t)lk * 16;
#pragma unroll
    for (int i = 0; i < 32; ++i)
      asm volatile("global_load_dwordx4 %0, %1, off sc0 sc1"
                   : "=v"(af[i]) : "v"(hbase + (size_t)i * 64));

    // ---- MFMA: 32 ksteps x 4 gate-tiles, vmcnt-gated groups of 8 ----
    f32x4 acc[4] = {};
#define MFMA_GRP(G)                                                                        \
    _Pragma("unroll")                                                                      \
    for (int ii = 0; ii < 8; ++ii) {                                                       \
      int i = (G) * 8 + ii;                                                                \
      _Pragma("unroll")                                                                    \
      for (int nt = 0; nt < 4; ++nt) {                                                     \
        bf16x8 bb = *(const bf16x8*)&whl[((i * 4 + lk) * 64 + nt * 16 + lr) * 8];          \
        acc[nt] = __builtin_amdgcn_mfma_f32_16x16x32_bf16(af[i], bb, acc[nt], 0, 0, 0);    \
      }                                                                                    \
    }
    asm volatile("s_waitcnt vmcnt(24)" ::: "memory");
    __builtin_amdgcn_sched_barrier(0);
    MFMA_GRP(0)
    asm volatile("s_waitcnt vmcnt(16)" ::: "memory");
    __builtin_amdgcn_sched_barrier(0);
    MFMA_GRP(1)
    asm volatile("s_waitcnt vmcnt(8)" ::: "memory");
    __builtin_amdgcn_sched_barrier(0);
    MFMA_GRP(2)
    asm volatile("s_waitcnt vmcnt(0)" ::: "memory");
    __builtin_amdgcn_sched_barrier(0);
    MFMA_GRP(3)
#undef MFMA_GRP

    // ---- gates + state + publish: lanes lk<2 own clean C-rows (tile rows 0-7) ----
    if (lk < 2) {
      int row0 = w * 8 + lk * 4;
      float hv[4];
#pragma unroll
      for (int r = 0; r < 4; ++r) {
        unsigned xlo = (unsigned)xq[r], xhi = (unsigned)(xq[r] >> 32);
        float gi = acc[0][r] + lo2f(xlo) + bias[0];
        float gf = acc[1][r] + hi2f(xlo) + bias[1];
        float gg = acc[2][r] + lo2f(xhi) + bias[2];
        float go = acc[3][r] + hi2f(xhi) + bias[3];
        cs[r] = sigmoidf_(gf) * cs[r] + sigmoidf_(gi) * tanhf_(gg);
        hv[r] = sigmoidf_(go) * tanhf_(cs[r]);
      }
      if (t == T_ - 1) {
#pragma unroll
        for (int r = 0; r < 4; ++r) {
          out[(size_t)(row0 + r) * H_ + ug] = hv[r];
          out[(size_t)B_ * H_ + (size_t)(row0 + r) * H_ + ug] = cs[r];
        }
      } else {
        // publish: 16 lanes x 2B contiguous per row = one 32B sector
        const char* hn = hb_c + (size_t)((t + 1) & 1) * 131072;
#pragma unroll
        for (int r = 0; r < 4; ++r) {
          unsigned hbv = (unsigned)b2s((bf16)hv[r]);
          const char* pa = hn + (size_t)(row0 + r) * 2048 + (size_t)ug * 2;
          asm volatile("global_store_short %0, %1, off sc0 sc1" :: "v"(pa), "v"(hbv) : "memory");
        }
      }
    }
    if (t == T_ - 1) break;

    // ---- per-wave drain + arm own flag (no block-wide sync) ----
    asm volatile("s_waitcnt vmcnt(0)" ::: "memory");
    if (lane == 0) {
      unsigned tv = (unsigned)(t + 1);
      const char* fa = flg + ((size_t)w * 64 + blk) * 32;
      asm volatile("global_store_dword %0, %1, off sc0 sc1" :: "v"(fa), "v"(tv) : "memory");
    }

    // ---- prefetch xg(t+1): lands under next poll ----
    {
      const char* xb = xg_c + (((size_t)(t + 1) * NBL + blk) * B_ + xrow) * 128 + (size_t)lr * 8;
#pragma unroll
      for (int r = 0; r < 4; ++r)
        asm volatile("global_load_dwordx2 %0, %1, off" : "=v"(xq[r]) : "v"(xb + (size_t)r * 128));
    }
  }
}

// ---------------- launcher ----------------

extern "C" void kernel_launch(void* const* d_in, const int* in_sizes, int n_in,
                              void* d_out, int out_size, void* d_ws, size_t ws_size,
                              hipStream_t stream) {
  if (ws_size < WS_NEED) return;

  const float* x = (const float*)d_in[0];
  const float* W_ii = (const float*)d_in[1];
  const float* W_hi = (const float*)d_in[2];
  const float* W_if = (const float*)d_in[3];
  const float* W_hf = (const float*)d_in[4];
  const float* W_ig = (const float*)d_in[5];
  const float* W_hg = (const float*)d_in[6];
  const float* W_io = (const float*)d_in[7];
  const float* W_ho = (const float*)d_in[8];
  const float* b_ii = (const float*)d_in[9];
  const float* b_hi = (const float*)d_in[10];
  const float* b_if = (const float*)d_in[11];
  const float* b_hf = (const float*)d_in[12];
  const float* b_ig = (const float*)d_in[13];
  const float* b_hg = (const float*)d_in[14];
  const float* b_io = (const float*)d_in[15];
  const float* b_ho = (const float*)d_in[16];

  char* ws = (char*)d_ws;
  bf16* xbf = (bf16*)(ws + WS_XBF);
  bf16* wxp = (bf16*)(ws + WS_WXP);
  bf16* whp = (bf16*)(ws + WS_WHP);
  bf16* xgp = (bf16*)(ws + WS_XG);
  bf16* hbp = (bf16*)(ws + WS_HB);
  unsigned* arrp = (unsigned*)(ws + WS_ARR);
  float* outp = (float*)d_out;

  // zero h0 buffers + flags (contiguous region)
  hipMemsetAsync(ws + WS_HB, 0, 262144 + 16384, stream);

  // pack
  k_cvt_x<<<2048, 256, 0, stream>>>((const float4*)x, xbf, BT_ * I_ / 4);
  const float* wx_g[4] = {W_ii, W_if, W_ig, W_io};
  const float* wh_g[4] = {W_hi, W_hf, W_hg, W_ho};
  for (int g = 0; g < 4; ++g) {
    k_pack_wx<<<1024, 256, 0, stream>>>(wx_g[g], wxp, g);
    k_pack_wh<<<1024, 256, 0, stream>>>(wh_g[g], whp, g);
  }

  // phase 1 GEMM
  k_gemm_xg<<<dim3(256 * 32), 256, 0, stream>>>(xbf, wxp, xgp);

  // phase 2 cooperative scan: 64 blocks x 512 threads
  void* args[] = {
      (void*)&xgp, (void*)&whp, (void*)&hbp, (void*)&outp, (void*)&arrp,
      (void*)&b_ii, (void*)&b_hi, (void*)&b_if, (void*)&b_hf,
      (void*)&b_ig, (void*)&b_hg, (void*)&b_io, (void*)&b_ho};
  hipLaunchCooperativeKernel((const void*)k_lstm, dim3(NBL), dim3(512), args, 0, stream);
}